// Round 16
// baseline (77.873 us; speedup 1.0000x reference)
//
#include <hip/hip_runtime.h>
#include <hip/hip_bf16.h>
#include <math.h>

#define NP 16
#define NB 512
#define ND 2048
#define NM (NP*NB)          // 8192 rows
#define BM 64
#define BN 128
#define BK 64               // 64 k-elems = 64 bytes per row per step (fp8)
#define NS (ND/BK)          // 32 K-steps
#define NCB (NB/BN)         // 4 col-blocks
#define NGB ((NM/BM)*NCB)   // 512 gemm blocks

typedef __attribute__((ext_vector_type(4))) float f32x4;
typedef unsigned int u32;

__device__ inline float dot4(float4 v) {
    return v.x * v.x + v.y * v.y + v.z * v.z + v.w * v.w;
}

// ---- f32x4 -> 4 packed OCP e4m3fn bytes (HW cvt; RNE, saturating) --------
#if __has_builtin(__builtin_amdgcn_cvt_pk_fp8_f32)
__device__ inline u32 pack4_fp8(float a, float b, float c, float d) {
    int w = 0;
    w = __builtin_amdgcn_cvt_pk_fp8_f32(a, b, w, false);  // bytes 0,1
    w = __builtin_amdgcn_cvt_pk_fp8_f32(c, d, w, true);   // bytes 2,3
    return (u32)w;
}
#else
#include <hip/hip_fp8.h>
__device__ inline u32 pack4_fp8(float a, float b, float c, float d) {
    u32 w  = (u32)__hip_cvt_float_to_fp8(a, __HIP_SATFINITE, __HIP_E4M3);
    w |= (u32)__hip_cvt_float_to_fp8(b, __HIP_SATFINITE, __HIP_E4M3) << 8;
    w |= (u32)__hip_cvt_float_to_fp8(c, __HIP_SATFINITE, __HIP_E4M3) << 16;
    w |= (u32)__hip_cvt_float_to_fp8(d, __HIP_SATFINITE, __HIP_E4M3) << 24;
    return w;
}
#endif

// ---------------------------------------------------------------------------
// Prep (d-sliced, R14-verified): block = batch col b, 512 thr = 8 waves; wave
// owns a 256-float d-slice; 16 patch values in registers; z-partial
// wave-local; <1 KB through LDS; one barrier pair. Block 0 zeroes cntr.
__global__ __launch_bounds__(512) void prep_kernel(
        const float* __restrict__ feat,
        unsigned char* __restrict__ an,      // [NM][ND] fp8, row-normalized
        unsigned char* __restrict__ zn,      // [NB][ND] fp8, row-normalized
        u32* __restrict__ cntr) {
    const int b = blockIdx.x, tid = threadIdx.x;
    const int lane = tid & 63, wv = tid >> 6;
    if (b == 0 && tid == 0) cntr[0] = 0u;

    const int dbase = wv * 256 + lane * 4;           // float index within row
    const float4* fp4 = (const float4*)feat;

    float4 rv[16];
    float4 z = make_float4(0.f, 0.f, 0.f, 0.f);
#pragma unroll
    for (int p = 0; p < NP; ++p) {
        rv[p] = fp4[((size_t)(p * NB + b) * ND + dbase) >> 2];
        z.x += rv[p].x; z.y += rv[p].y; z.z += rv[p].z; z.w += rv[p].w;
    }

    __shared__ float sm_ssq[NP][8];
    __shared__ float sm_z[8];
    __shared__ float sm_inv[NP + 1];
#pragma unroll
    for (int p = 0; p < NP; ++p) {
        float ss = dot4(rv[p]);
#pragma unroll
        for (int off = 32; off > 0; off >>= 1) ss += __shfl_xor(ss, off);
        if (lane == 0) sm_ssq[p][wv] = ss;
    }
    {
        float zs = dot4(z);
#pragma unroll
        for (int off = 32; off > 0; off >>= 1) zs += __shfl_xor(zs, off);
        if (lane == 0) sm_z[wv] = zs;
    }
    __syncthreads();
    if (tid < NP) {
        float t = 0.f;
#pragma unroll
        for (int v = 0; v < 8; ++v) t += sm_ssq[tid][v];
        sm_inv[tid] = 1.f / fmaxf(sqrtf(t), 1e-12f);
    } else if (tid == NP) {
        float t = 0.f;
#pragma unroll
        for (int v = 0; v < 8; ++v) t += sm_z[v];
        sm_inv[NP] = 1.f / fmaxf(sqrtf(t), 1e-12f);
    }
    __syncthreads();

#pragma unroll
    for (int p = 0; p < NP; ++p) {
        const float inv = sm_inv[p];
        ((u32*)(an + (size_t)(p * NB + b) * ND))[dbase >> 2] =
            pack4_fp8(rv[p].x * inv, rv[p].y * inv, rv[p].z * inv, rv[p].w * inv);
    }
    const float iz = sm_inv[NP];
    ((u32*)(zn + (size_t)b * ND))[dbase >> 2] =
        pack4_fp8(z.x * iz, z.y * iz, z.z * iz, z.w * iz);
}

// ---------------------------------------------------------------------------
// GEMM + partial CE loss + LAST-BLOCK final reduce. Gemm body identical to
// R14 (passing). After partial writes: __threadfence (device-scope release)
// + atomicAdd(cntr); the block observing old==NGB-1 reads all partials
// (release/acquire pattern identical to R13/R14's cross-kernel reduce) and
// computes the final loss in a FIXED order (deterministic regardless of
// which block finishes last), writing out[0] directly.
__global__ __launch_bounds__(256, 2) void gemm_loss_kernel(
        const unsigned char* __restrict__ an, // [NM][ND] fp8
        const unsigned char* __restrict__ zn, // [NB][ND] fp8
        float* __restrict__ pmax_g,           // [NCB][NM]
        float* __restrict__ psum_g,           // [NCB][NM]
        float* __restrict__ ppos_g,           // [NM]
        u32* __restrict__ cntr,
        float* __restrict__ out) {
    __shared__ __align__(16) unsigned char abuf[3 * BM * BK];  // 3 x 4 KB
    __shared__ __align__(16) unsigned char bbuf[3 * BN * BK];  // 3 x 8 KB
    __shared__ float sm_max[BM][2];
    __shared__ float sm_sum[BM][2];
    __shared__ float sm_pos[BM];
    __shared__ int   sm_last;
    __shared__ float sm_part[4];

    const int tid  = threadIdx.x;
    const int lane = tid & 63;
    const int w    = tid >> 6;       // 0..3
    const int wr   = w >> 1;         // row strip 0..1 (32 rows each)
    const int wc   = w & 1;          // col strip 0..1 (64 cols each)
    const int l15  = lane & 15;
    const int l4   = lane >> 4;      // 0..3
    const int cb   = blockIdx.x & (NCB - 1);
    const int brow = (blockIdx.x >> 2) * BM;
    const int bcol = cb * BN;

    f32x4 acc[2][4] = {};

    const int sra = tid >> 2;                        // A row 0..63
    const int sca = (tid & 3) ^ ((sra >> 2) & 3);    // swizzled granule
    const unsigned char* asrc = an + (size_t)(brow + sra) * ND + sca * 16;
    const unsigned char* bsrc0;
    const unsigned char* bsrc1;
    {
        int q0 = tid, q1 = 256 + tid;
        int r0 = q0 >> 2, c0 = (q0 & 3) ^ ((r0 >> 2) & 3);
        int r1 = q1 >> 2, c1 = (q1 & 3) ^ ((r1 >> 2) & 3);
        bsrc0 = zn + (size_t)(bcol + r0) * ND + c0 * 16;
        bsrc1 = zn + (size_t)(bcol + r1) * ND + c1 * 16;
    }

#define STAGE(BI, S) do {                                                     \
        const int koB_ = (S) * BK;                                            \
        __builtin_amdgcn_global_load_lds((const u32*)(asrc + koB_),           \
            (u32*)(&abuf[(BI) * 4096 + tid * 16]), 16, 0, 0);                 \
        __builtin_amdgcn_global_load_lds((const u32*)(bsrc0 + koB_),          \
            (u32*)(&bbuf[(BI) * 8192 + tid * 16]), 16, 0, 0);                 \
        __builtin_amdgcn_global_load_lds((const u32*)(bsrc1 + koB_),          \
            (u32*)(&bbuf[(BI) * 8192 + 4096 + tid * 16]), 16, 0, 0);          \
    } while (0)

    STAGE(0, 0);
    STAGE(1, 1);

    int acur = 0, astg = 2;
    for (int s = 0; s < NS; ++s) {
        if (s + 1 < NS) asm volatile("s_waitcnt vmcnt(3)" ::: "memory");
        else            asm volatile("s_waitcnt vmcnt(0)" ::: "memory");
        __builtin_amdgcn_sched_barrier(0);
        __builtin_amdgcn_s_barrier();          // buf staged by ALL waves;
        __builtin_amdgcn_sched_barrier(0);     // prev-step reads all retired

        long long af[2][2], bf[2][4];
#pragma unroll
        for (int kc = 0; kc < 2; ++kc) {
            const int kk = kc * 4 + l4;
#pragma unroll
            for (int m = 0; m < 2; ++m) {
                int r = wr * 32 + m * 16 + l15;
                int g = (kk >> 1) ^ ((r >> 2) & 3);
                af[kc][m] = *(const long long*)(
                    &abuf[acur * 4096 + r * 64 + g * 16 + (kk & 1) * 8]);
            }
#pragma unroll
            for (int n = 0; n < 4; ++n) {
                int r = wc * 64 + n * 16 + l15;
                int g = (kk >> 1) ^ ((r >> 2) & 3);
                bf[kc][n] = *(const long long*)(
                    &bbuf[acur * 8192 + r * 64 + g * 16 + (kk & 1) * 8]);
            }
        }

        if (s + 2 < NS) STAGE(astg, s + 2);    // DMA flies under the MFMAs

        __builtin_amdgcn_s_setprio(1);
#pragma unroll
        for (int kc = 0; kc < 2; ++kc)
#pragma unroll
        for (int m = 0; m < 2; ++m)
#pragma unroll
        for (int n = 0; n < 4; ++n)
            acc[m][n] = __builtin_amdgcn_mfma_f32_16x16x32_fp8_fp8(
                af[kc][m], bf[kc][n], acc[m][n], 0, 0, 0);
        __builtin_amdgcn_s_setprio(0);

        acur = (acur == 2) ? 0 : acur + 1;
        astg = (astg == 2) ? 0 : astg + 1;
    }
#undef STAGE

    // ---- epilogue: partial logsumexp over this block's 128 cols ----
#pragma unroll
    for (int m = 0; m < 2; ++m) {
#pragma unroll
        for (int r = 0; r < 4; ++r) {
            const int lrow = wr * 32 + m * 16 + l4 * 4 + r;   // local row 0..63
            float lg[4];
            float mx = -1e30f;
#pragma unroll
            for (int n = 0; n < 4; ++n) {
                lg[n] = acc[m][n][r] * 5.0f;                  // /TEMP
                mx = fmaxf(mx, lg[n]);
            }
            mx = fmaxf(mx, __shfl_xor(mx, 1));
            mx = fmaxf(mx, __shfl_xor(mx, 2));
            mx = fmaxf(mx, __shfl_xor(mx, 4));
            mx = fmaxf(mx, __shfl_xor(mx, 8));
            float se = 0.f;
#pragma unroll
            for (int n = 0; n < 4; ++n) se += __expf(lg[n] - mx);
            se += __shfl_xor(se, 1);
            se += __shfl_xor(se, 2);
            se += __shfl_xor(se, 4);
            se += __shfl_xor(se, 8);
            if (l15 == 0) { sm_max[lrow][wc] = mx; sm_sum[lrow][wc] = se; }
            const int posc = (brow + lrow) & (NB - 1);        // global row % 512
#pragma unroll
            for (int n = 0; n < 4; ++n)
                if (bcol + wc * 64 + n * 16 + l15 == posc) sm_pos[lrow] = lg[n];
        }
    }
    __syncthreads();

    if (tid < BM) {
        const int lrow = tid;
        const int grow = brow + lrow;
        const float m0 = sm_max[lrow][0], m1 = sm_max[lrow][1];
        const float gm = fmaxf(m0, m1);
        const float tot = sm_sum[lrow][0] * __expf(m0 - gm)
                        + sm_sum[lrow][1] * __expf(m1 - gm);
        pmax_g[cb * NM + grow] = gm;
        psum_g[cb * NM + grow] = tot;
        if (((grow & (NB - 1)) >> 7) == cb) ppos_g[grow] = sm_pos[lrow];
    }

    // ---- last-block-done final reduce ----
    __threadfence();                           // release partial writes
    if (tid == 0) {
        u32 old = atomicAdd(cntr, 1u);
        sm_last = (old == (u32)(NGB - 1)) ? 1 : 0;
    }
    __syncthreads();
    if (sm_last) {
        float term = 0.f;
#pragma unroll
        for (int it = 0; it < NM / 256; ++it) {       // 32 iterations
            const int row = it * 256 + tid;
            float m0 = pmax_g[row],          m1 = pmax_g[NM + row];
            float m2 = pmax_g[2 * NM + row], m3 = pmax_g[3 * NM + row];
            float gm = fmaxf(fmaxf(m0, m1), fmaxf(m2, m3));
            float tot = psum_g[row]          * __expf(m0 - gm)
                      + psum_g[NM + row]     * __expf(m1 - gm)
                      + psum_g[2 * NM + row] * __expf(m2 - gm)
                      + psum_g[3 * NM + row] * __expf(m3 - gm);
            term += gm + __logf(tot) - ppos_g[row];
        }
#pragma unroll
        for (int off = 32; off > 0; off >>= 1) term += __shfl_xor(term, off);
        if (lane == 0) sm_part[w] = term;
        __syncthreads();
        if (tid == 0)
            out[0] = (sm_part[0] + sm_part[1] + sm_part[2] + sm_part[3])
                     * (1.0f / (float)NM);
    }
}

extern "C" void kernel_launch(void* const* d_in, const int* in_sizes, int n_in,
                              void* d_out, int out_size, void* d_ws, size_t ws_size,
                              hipStream_t stream) {
    const float* feat = (const float*)d_in[0];

    unsigned char* an = (unsigned char*)d_ws;              // 16 MB fp8
    unsigned char* zn = an + (size_t)NM * ND;              // 1 MB fp8
    float* pmax = (float*)(zn + (size_t)NB * ND);          // NCB*NM
    float* psum = pmax + NCB * NM;                         // NCB*NM
    float* ppos = psum + NCB * NM;                         // NM
    u32*   cntr = (u32*)(ppos + NM);                       // 1 u32

    prep_kernel<<<NB, 512, 0, stream>>>(feat, an, zn, cntr);
    gemm_loss_kernel<<<NGB, 256, 0, stream>>>(an, zn, pmax, psum, ppos, cntr,
                                              (float*)d_out);
}

// Round 17
// 51.326 us; speedup vs baseline: 1.5172x; 1.5172x over previous
//
#include <hip/hip_runtime.h>
#include <hip/hip_bf16.h>
#include <math.h>

#define NP 16
#define NB 512
#define ND 2048
#define NM (NP*NB)          // 8192 rows
#define BM 64
#define BN 128
#define BK 64               // 64 k-elems = 64 bytes per row per step (fp8)
#define NS (ND/BK)          // 32 K-steps
#define NCB (NB/BN)         // 4 col-blocks

typedef __attribute__((ext_vector_type(4))) float f32x4;
typedef unsigned int u32;

__device__ inline float dot4(float4 v) {
    return v.x * v.x + v.y * v.y + v.z * v.z + v.w * v.w;
}

// ---- f32x4 -> 4 packed OCP e4m3fn bytes (HW cvt; RNE, saturating) --------
#if __has_builtin(__builtin_amdgcn_cvt_pk_fp8_f32)
__device__ inline u32 pack4_fp8(float a, float b, float c, float d) {
    int w = 0;
    w = __builtin_amdgcn_cvt_pk_fp8_f32(a, b, w, false);  // bytes 0,1
    w = __builtin_amdgcn_cvt_pk_fp8_f32(c, d, w, true);   // bytes 2,3
    return (u32)w;
}
#else
#include <hip/hip_fp8.h>
__device__ inline u32 pack4_fp8(float a, float b, float c, float d) {
    u32 w  = (u32)__hip_cvt_float_to_fp8(a, __HIP_SATFINITE, __HIP_E4M3);
    w |= (u32)__hip_cvt_float_to_fp8(b, __HIP_SATFINITE, __HIP_E4M3) << 8;
    w |= (u32)__hip_cvt_float_to_fp8(c, __HIP_SATFINITE, __HIP_E4M3) << 16;
    w |= (u32)__hip_cvt_float_to_fp8(d, __HIP_SATFINITE, __HIP_E4M3) << 24;
    return w;
}
#endif

// ---------------------------------------------------------------------------
// Prep (d-sliced, R14-verified): block = batch col b, 512 thr = 8 waves; wave
// owns a 256-float d-slice; 16 patch values in registers; z-partial
// wave-local; <1 KB through LDS; one barrier pair. Block 0 zeroes acc+cntr.
__global__ __launch_bounds__(512) void prep_kernel(
        const float* __restrict__ feat,
        unsigned char* __restrict__ an,      // [NM][ND] fp8, row-normalized
        unsigned char* __restrict__ zn,      // [NB][ND] fp8, row-normalized
        float* __restrict__ accg, u32* __restrict__ cntr) {
    const int b = blockIdx.x, tid = threadIdx.x;
    const int lane = tid & 63, wv = tid >> 6;
    if (b == 0 && tid == 0) { accg[0] = 0.f; cntr[0] = 0u; }

    const int dbase = wv * 256 + lane * 4;           // float index within row
    const float4* fp4 = (const float4*)feat;

    float4 rv[16];
    float4 z = make_float4(0.f, 0.f, 0.f, 0.f);
#pragma unroll
    for (int p = 0; p < NP; ++p) {
        rv[p] = fp4[((size_t)(p * NB + b) * ND + dbase) >> 2];
        z.x += rv[p].x; z.y += rv[p].y; z.z += rv[p].z; z.w += rv[p].w;
    }

    __shared__ float sm_ssq[NP][8];
    __shared__ float sm_z[8];
    __shared__ float sm_inv[NP + 1];
#pragma unroll
    for (int p = 0; p < NP; ++p) {
        float ss = dot4(rv[p]);
#pragma unroll
        for (int off = 32; off > 0; off >>= 1) ss += __shfl_xor(ss, off);
        if (lane == 0) sm_ssq[p][wv] = ss;
    }
    {
        float zs = dot4(z);
#pragma unroll
        for (int off = 32; off > 0; off >>= 1) zs += __shfl_xor(zs, off);
        if (lane == 0) sm_z[wv] = zs;
    }
    __syncthreads();
    if (tid < NP) {
        float t = 0.f;
#pragma unroll
        for (int v = 0; v < 8; ++v) t += sm_ssq[tid][v];
        sm_inv[tid] = 1.f / fmaxf(sqrtf(t), 1e-12f);
    } else if (tid == NP) {
        float t = 0.f;
#pragma unroll
        for (int v = 0; v < 8; ++v) t += sm_z[v];
        sm_inv[NP] = 1.f / fmaxf(sqrtf(t), 1e-12f);
    }
    __syncthreads();

#pragma unroll
    for (int p = 0; p < NP; ++p) {
        const float inv = sm_inv[p];
        ((u32*)(an + (size_t)(p * NB + b) * ND))[dbase >> 2] =
            pack4_fp8(rv[p].x * inv, rv[p].y * inv, rv[p].z * inv, rv[p].w * inv);
    }
    const float iz = sm_inv[NP];
    ((u32*)(zn + (size_t)b * ND))[dbase >> 2] =
        pack4_fp8(z.x * iz, z.y * iz, z.z * iz, z.w * iz);
}

// ---------------------------------------------------------------------------
// GEMM + partial CE loss, fp8 e4m3 (R14 structure, passing). Block = 64x128,
// 256 thr = 4 waves (2x2), wave tile 32x64 (acc[2][4]), 2 blocks/CU.
// 3 LDS buffers, 2-deep global_load_lds staging, ONE barrier + counted
// vmcnt(3) per step. R17 deltas: (a) STAGE issued right after the barrier
// (before ds_reads) so the DMA overlaps reads+MFMA; (b) manual 3-step unroll
// with LITERAL buffer indices (no runtime acur/astg rotation).
__global__ __launch_bounds__(256, 2) void gemm_loss_kernel(
        const unsigned char* __restrict__ an, // [NM][ND] fp8
        const unsigned char* __restrict__ zn, // [NB][ND] fp8
        float* __restrict__ pmax_g,           // [NCB][NM]
        float* __restrict__ psum_g,           // [NCB][NM]
        float* __restrict__ ppos_g) {         // [NM]
    __shared__ __align__(16) unsigned char abuf[3 * BM * BK];  // 3 x 4 KB
    __shared__ __align__(16) unsigned char bbuf[3 * BN * BK];  // 3 x 8 KB
    __shared__ float sm_max[BM][2];
    __shared__ float sm_sum[BM][2];
    __shared__ float sm_pos[BM];

    const int tid  = threadIdx.x;
    const int lane = tid & 63;
    const int w    = tid >> 6;       // 0..3
    const int wr   = w >> 1;         // row strip 0..1 (32 rows each)
    const int wc   = w & 1;          // col strip 0..1 (64 cols each)
    const int l15  = lane & 15;
    const int l4   = lane >> 4;      // 0..3
    const int cb   = blockIdx.x & (NCB - 1);
    const int brow = (blockIdx.x >> 2) * BM;
    const int bcol = cb * BN;

    f32x4 acc[2][4] = {};

    const int sra = tid >> 2;                        // A row 0..63
    const int sca = (tid & 3) ^ ((sra >> 2) & 3);    // swizzled granule
    const unsigned char* asrc = an + (size_t)(brow + sra) * ND + sca * 16;
    const unsigned char* bsrc0;
    const unsigned char* bsrc1;
    {
        int q0 = tid, q1 = 256 + tid;
        int r0 = q0 >> 2, c0 = (q0 & 3) ^ ((r0 >> 2) & 3);
        int r1 = q1 >> 2, c1 = (q1 & 3) ^ ((r1 >> 2) & 3);
        bsrc0 = zn + (size_t)(bcol + r0) * ND + c0 * 16;
        bsrc1 = zn + (size_t)(bcol + r1) * ND + c1 * 16;
    }

#define STAGE(BI, S) do {                                                     \
        const int koB_ = (S) * BK;                                            \
        __builtin_amdgcn_global_load_lds((const u32*)(asrc + koB_),           \
            (u32*)(&abuf[(BI) * 4096 + tid * 16]), 16, 0, 0);                 \
        __builtin_amdgcn_global_load_lds((const u32*)(bsrc0 + koB_),          \
            (u32*)(&bbuf[(BI) * 8192 + tid * 16]), 16, 0, 0);                 \
        __builtin_amdgcn_global_load_lds((const u32*)(bsrc1 + koB_),          \
            (u32*)(&bbuf[(BI) * 8192 + 4096 + tid * 16]), 16, 0, 0);          \
    } while (0)

// One K-step. RB/SB are LITERAL buffer indices; stage issued BEFORE reads.
// vmcnt(3): stage(s) complete, stage(s+1)'s 3 loads may stay in flight.
// Overwrite safety (R14-proven): step-s reads are consumed by step-s MFMAs
// before the step-(s+1) barrier; stage(s+2) targets neither s%3 nor (s+1)%3.
#define STEP(S, RB, SB, DO_STAGE, VMN) do {                                   \
        asm volatile("s_waitcnt vmcnt(" #VMN ")" ::: "memory");               \
        __builtin_amdgcn_sched_barrier(0);                                    \
        __builtin_amdgcn_s_barrier();                                         \
        __builtin_amdgcn_sched_barrier(0);                                    \
        if (DO_STAGE) STAGE(SB, (S) + 2);                                     \
        long long af[2][2], bf[2][4];                                         \
        _Pragma("unroll")                                                     \
        for (int kc = 0; kc < 2; ++kc) {                                      \
            const int kk = kc * 4 + l4;                                       \
            _Pragma("unroll")                                                 \
            for (int m = 0; m < 2; ++m) {                                     \
                int r = wr * 32 + m * 16 + l15;                               \
                int g = (kk >> 1) ^ ((r >> 2) & 3);                           \
                af[kc][m] = *(const long long*)(                              \
                    &abuf[(RB) * 4096 + r * 64 + g * 16 + (kk & 1) * 8]);     \
            }                                                                 \
            _Pragma("unroll")                                                 \
            for (int n = 0; n < 4; ++n) {                                     \
                int r = wc * 64 + n * 16 + l15;                               \
                int g = (kk >> 1) ^ ((r >> 2) & 3);                           \
                bf[kc][n] = *(const long long*)(                              \
                    &bbuf[(RB) * 8192 + r * 64 + g * 16 + (kk & 1) * 8]);     \
            }                                                                 \
        }                                                                     \
        __builtin_amdgcn_s_setprio(1);                                        \
        _Pragma("unroll")                                                     \
        for (int kc = 0; kc < 2; ++kc)                                        \
        _Pragma("unroll")                                                     \
        for (int m = 0; m < 2; ++m)                                           \
        _Pragma("unroll")                                                     \
        for (int n = 0; n < 4; ++n)                                           \
            acc[m][n] = __builtin_amdgcn_mfma_f32_16x16x32_fp8_fp8(           \
                af[kc][m], bf[kc][n], acc[m][n], 0, 0, 0);                    \
        __builtin_amdgcn_s_setprio(0);                                        \
    } while (0)

    STAGE(0, 0);
    STAGE(1, 1);

    for (int ss = 0; ss < NS - 2; ss += 3) {     // steps 0..29
        STEP(ss,     0, 2, true, 3);
        STEP(ss + 1, 1, 0, true, 3);
        STEP(ss + 2, 2, 1, true, 3);
    }
    STEP(NS - 2, 0, 2, false, 3);                // step 30, buf 0
    STEP(NS - 1, 1, 0, false, 0);                // step 31, buf 1
#undef STEP
#undef STAGE

    // ---- epilogue: partial logsumexp over this block's 128 cols ----
#pragma unroll
    for (int m = 0; m < 2; ++m) {
#pragma unroll
        for (int r = 0; r < 4; ++r) {
            const int lrow = wr * 32 + m * 16 + l4 * 4 + r;   // local row 0..63
            float lg[4];
            float mx = -1e30f;
#pragma unroll
            for (int n = 0; n < 4; ++n) {
                lg[n] = acc[m][n][r] * 5.0f;                  // /TEMP
                mx = fmaxf(mx, lg[n]);
            }
            mx = fmaxf(mx, __shfl_xor(mx, 1));
            mx = fmaxf(mx, __shfl_xor(mx, 2));
            mx = fmaxf(mx, __shfl_xor(mx, 4));
            mx = fmaxf(mx, __shfl_xor(mx, 8));
            float se = 0.f;
#pragma unroll
            for (int n = 0; n < 4; ++n) se += __expf(lg[n] - mx);
            se += __shfl_xor(se, 1);
            se += __shfl_xor(se, 2);
            se += __shfl_xor(se, 4);
            se += __shfl_xor(se, 8);
            if (l15 == 0) { sm_max[lrow][wc] = mx; sm_sum[lrow][wc] = se; }
            const int posc = (brow + lrow) & (NB - 1);        // global row % 512
#pragma unroll
            for (int n = 0; n < 4; ++n)
                if (bcol + wc * 64 + n * 16 + l15 == posc) sm_pos[lrow] = lg[n];
        }
    }
    __syncthreads();

    if (tid < BM) {
        const int lrow = tid;
        const int grow = brow + lrow;
        const float m0 = sm_max[lrow][0], m1 = sm_max[lrow][1];
        const float gm = fmaxf(m0, m1);
        const float tot = sm_sum[lrow][0] * __expf(m0 - gm)
                        + sm_sum[lrow][1] * __expf(m1 - gm);
        pmax_g[cb * NM + grow] = gm;
        psum_g[cb * NM + grow] = tot;
        if (((grow & (NB - 1)) >> 7) == cb) ppos_g[grow] = sm_pos[lrow];
    }
}

// ---------------------------------------------------------------------------
// Combine 4 col-block partials per row -> loss; last block writes d_out.
__global__ __launch_bounds__(256) void reduce_kernel(
        const float* __restrict__ pmax_g, const float* __restrict__ psum_g,
        const float* __restrict__ ppos_g, float* __restrict__ acc_g,
        u32* __restrict__ counter, float* __restrict__ out) {
    const int row = blockIdx.x * 256 + threadIdx.x;   // 32 blocks x 256
    float mxs[NCB];
    float gm = -1e30f;
#pragma unroll
    for (int c = 0; c < NCB; ++c) {
        mxs[c] = pmax_g[c * NM + row];
        gm = fmaxf(gm, mxs[c]);
    }
    float tot = 0.f;
#pragma unroll
    for (int c = 0; c < NCB; ++c)
        tot += psum_g[c * NM + row] * __expf(mxs[c] - gm);
    float term = gm + __logf(tot) - ppos_g[row];
#pragma unroll
    for (int off = 32; off > 0; off >>= 1) term += __shfl_xor(term, off);
    __shared__ float wsum[4];
    const int lane = threadIdx.x & 63, wv = threadIdx.x >> 6;
    if (lane == 0) wsum[wv] = term;
    __syncthreads();
    if (threadIdx.x == 0) {
        atomicAdd(acc_g, wsum[0] + wsum[1] + wsum[2] + wsum[3]);
        __threadfence();
        u32 old = atomicAdd(counter, 1u);
        if (old == 31u) {                       // last block: all adds visible
            float total = atomicAdd(acc_g, 0.0f);
            out[0] = total * (1.0f / (float)NM);
        }
    }
}

extern "C" void kernel_launch(void* const* d_in, const int* in_sizes, int n_in,
                              void* d_out, int out_size, void* d_ws, size_t ws_size,
                              hipStream_t stream) {
    const float* feat = (const float*)d_in[0];

    unsigned char* an = (unsigned char*)d_ws;              // 16 MB fp8
    unsigned char* zn = an + (size_t)NM * ND;              // 1 MB fp8
    float* pmax = (float*)(zn + (size_t)NB * ND);          // NCB*NM
    float* psum = pmax + NCB * NM;                         // NCB*NM
    float* ppos = psum + NCB * NM;                         // NM
    float* accg = ppos + NM;                               // 1 float
    u32*   cntr = (u32*)(accg + 1);                        // 1 u32

    prep_kernel<<<NB, 512, 0, stream>>>(feat, an, zn, accg, cntr);
    gemm_loss_kernel<<<(NM / BM) * NCB, 256, 0, stream>>>(an, zn, pmax, psum, ppos);
    reduce_kernel<<<NM / 256, 256, 0, stream>>>(pmax, psum, ppos, accg, cntr,
                                                (float*)d_out);
}

// Round 18
// 44.515 us; speedup vs baseline: 1.7494x; 1.1530x over previous
//
#include <hip/hip_runtime.h>
#include <hip/hip_bf16.h>
#include <math.h>

#define NP 16
#define NB 512
#define ND 2048
#define NM (NP*NB)          // 8192 rows
#define BM 64
#define BN 128
#define BK 64               // 64 k-elems = 64 bytes per row per step (fp8)
#define NS (ND/BK)          // 32 K-steps
#define NCB (NB/BN)         // 4 col-blocks

typedef __attribute__((ext_vector_type(4))) float f32x4;
typedef unsigned int u32;

__device__ inline float dot4(float4 v) {
    return v.x * v.x + v.y * v.y + v.z * v.z + v.w * v.w;
}

// ---- f32x4 -> 4 packed OCP e4m3fn bytes (HW cvt; RNE, saturating) --------
#if __has_builtin(__builtin_amdgcn_cvt_pk_fp8_f32)
__device__ inline u32 pack4_fp8(float a, float b, float c, float d) {
    int w = 0;
    w = __builtin_amdgcn_cvt_pk_fp8_f32(a, b, w, false);  // bytes 0,1
    w = __builtin_amdgcn_cvt_pk_fp8_f32(c, d, w, true);   // bytes 2,3
    return (u32)w;
}
#else
#include <hip/hip_fp8.h>
__device__ inline u32 pack4_fp8(float a, float b, float c, float d) {
    u32 w  = (u32)__hip_cvt_float_to_fp8(a, __HIP_SATFINITE, __HIP_E4M3);
    w |= (u32)__hip_cvt_float_to_fp8(b, __HIP_SATFINITE, __HIP_E4M3) << 8;
    w |= (u32)__hip_cvt_float_to_fp8(c, __HIP_SATFINITE, __HIP_E4M3) << 16;
    w |= (u32)__hip_cvt_float_to_fp8(d, __HIP_SATFINITE, __HIP_E4M3) << 24;
    return w;
}
#endif

// ---------------------------------------------------------------------------
// Prep (d-sliced, R14-verified): block = batch col b, 512 thr = 8 waves; wave
// owns a 256-float d-slice; 16 patch values in registers; z-partial
// wave-local; <1 KB through LDS; one barrier pair. Block 0 zeroes acc+cntr.
__global__ __launch_bounds__(512) void prep_kernel(
        const float* __restrict__ feat,
        unsigned char* __restrict__ an,      // [NM][ND] fp8, row-normalized
        unsigned char* __restrict__ zn,      // [NB][ND] fp8, row-normalized
        float* __restrict__ accg, u32* __restrict__ cntr) {
    const int b = blockIdx.x, tid = threadIdx.x;
    const int lane = tid & 63, wv = tid >> 6;
    if (b == 0 && tid == 0) { accg[0] = 0.f; cntr[0] = 0u; }

    const int dbase = wv * 256 + lane * 4;           // float index within row
    const float4* fp4 = (const float4*)feat;

    float4 rv[16];
    float4 z = make_float4(0.f, 0.f, 0.f, 0.f);
#pragma unroll
    for (int p = 0; p < NP; ++p) {
        rv[p] = fp4[((size_t)(p * NB + b) * ND + dbase) >> 2];
        z.x += rv[p].x; z.y += rv[p].y; z.z += rv[p].z; z.w += rv[p].w;
    }

    __shared__ float sm_ssq[NP][8];
    __shared__ float sm_z[8];
    __shared__ float sm_inv[NP + 1];
#pragma unroll
    for (int p = 0; p < NP; ++p) {
        float ss = dot4(rv[p]);
#pragma unroll
        for (int off = 32; off > 0; off >>= 1) ss += __shfl_xor(ss, off);
        if (lane == 0) sm_ssq[p][wv] = ss;
    }
    {
        float zs = dot4(z);
#pragma unroll
        for (int off = 32; off > 0; off >>= 1) zs += __shfl_xor(zs, off);
        if (lane == 0) sm_z[wv] = zs;
    }
    __syncthreads();
    if (tid < NP) {
        float t = 0.f;
#pragma unroll
        for (int v = 0; v < 8; ++v) t += sm_ssq[tid][v];
        sm_inv[tid] = 1.f / fmaxf(sqrtf(t), 1e-12f);
    } else if (tid == NP) {
        float t = 0.f;
#pragma unroll
        for (int v = 0; v < 8; ++v) t += sm_z[v];
        sm_inv[NP] = 1.f / fmaxf(sqrtf(t), 1e-12f);
    }
    __syncthreads();

#pragma unroll
    for (int p = 0; p < NP; ++p) {
        const float inv = sm_inv[p];
        ((u32*)(an + (size_t)(p * NB + b) * ND))[dbase >> 2] =
            pack4_fp8(rv[p].x * inv, rv[p].y * inv, rv[p].z * inv, rv[p].w * inv);
    }
    const float iz = sm_inv[NP];
    ((u32*)(zn + (size_t)b * ND))[dbase >> 2] =
        pack4_fp8(z.x * iz, z.y * iz, z.z * iz, z.w * iz);
}

// ---------------------------------------------------------------------------
// GEMM + partial CE loss, fp8 e4m3 — EXACT R14 loop (read -> stage -> MFMA,
// runtime buffer rotation, ONE barrier + vmcnt(3)/step). New: (a) XCD-affinity
// block remap so the 4 col-blocks of one A row-panel share an XCD L2;
// (b) max-free softmax partials (|logit| <= ~5.2 -> exp cannot overflow).
__global__ __launch_bounds__(256, 2) void gemm_loss_kernel(
        const unsigned char* __restrict__ an, // [NM][ND] fp8
        const unsigned char* __restrict__ zn, // [NB][ND] fp8
        float* __restrict__ psum_g,           // [NCB][NM]
        float* __restrict__ ppos_g) {         // [NM]
    __shared__ __align__(16) unsigned char abuf[3 * BM * BK];  // 3 x 4 KB
    __shared__ __align__(16) unsigned char bbuf[3 * BN * BK];  // 3 x 8 KB
    __shared__ float sm_sum[BM][2];
    __shared__ float sm_pos[BM];

    const int tid  = threadIdx.x;
    const int lane = tid & 63;
    const int w    = tid >> 6;       // 0..3
    const int wr   = w >> 1;         // row strip 0..1 (32 rows each)
    const int wc   = w & 1;          // col strip 0..1 (64 cols each)
    const int l15  = lane & 15;
    const int l4   = lane >> 4;      // 0..3
    // XCD-affinity remap: xcd = bid&7 (default round-robin); all 4 cb's of a
    // row-panel map to the SAME xcd and are dispatched near-simultaneously.
    const int xcd    = blockIdx.x & 7;
    const int slot   = blockIdx.x >> 3;          // 0..63
    const int cb     = slot & 3;
    const int rowblk = xcd + 8 * (slot >> 2);    // 0..127, bijective
    const int brow = rowblk * BM;
    const int bcol = cb * BN;

    f32x4 acc[2][4] = {};

    const int sra = tid >> 2;                        // A row 0..63
    const int sca = (tid & 3) ^ ((sra >> 2) & 3);    // swizzled granule
    const unsigned char* asrc = an + (size_t)(brow + sra) * ND + sca * 16;
    const unsigned char* bsrc0;
    const unsigned char* bsrc1;
    {
        int q0 = tid, q1 = 256 + tid;
        int r0 = q0 >> 2, c0 = (q0 & 3) ^ ((r0 >> 2) & 3);
        int r1 = q1 >> 2, c1 = (q1 & 3) ^ ((r1 >> 2) & 3);
        bsrc0 = zn + (size_t)(bcol + r0) * ND + c0 * 16;
        bsrc1 = zn + (size_t)(bcol + r1) * ND + c1 * 16;
    }

#define STAGE(BI, S) do {                                                     \
        const int koB_ = (S) * BK;                                            \
        __builtin_amdgcn_global_load_lds((const u32*)(asrc + koB_),           \
            (u32*)(&abuf[(BI) * 4096 + tid * 16]), 16, 0, 0);                 \
        __builtin_amdgcn_global_load_lds((const u32*)(bsrc0 + koB_),          \
            (u32*)(&bbuf[(BI) * 8192 + tid * 16]), 16, 0, 0);                 \
        __builtin_amdgcn_global_load_lds((const u32*)(bsrc1 + koB_),          \
            (u32*)(&bbuf[(BI) * 8192 + 4096 + tid * 16]), 16, 0, 0);          \
    } while (0)

    STAGE(0, 0);
    STAGE(1, 1);

    int acur = 0, astg = 2;
    for (int s = 0; s < NS; ++s) {
        if (s + 1 < NS) asm volatile("s_waitcnt vmcnt(3)" ::: "memory");
        else            asm volatile("s_waitcnt vmcnt(0)" ::: "memory");
        __builtin_amdgcn_sched_barrier(0);
        __builtin_amdgcn_s_barrier();          // buf staged by ALL waves;
        __builtin_amdgcn_sched_barrier(0);     // prev-step reads all retired

        long long af[2][2], bf[2][4];
#pragma unroll
        for (int kc = 0; kc < 2; ++kc) {
            const int kk = kc * 4 + l4;
#pragma unroll
            for (int m = 0; m < 2; ++m) {
                int r = wr * 32 + m * 16 + l15;
                int g = (kk >> 1) ^ ((r >> 2) & 3);
                af[kc][m] = *(const long long*)(
                    &abuf[acur * 4096 + r * 64 + g * 16 + (kk & 1) * 8]);
            }
#pragma unroll
            for (int n = 0; n < 4; ++n) {
                int r = wc * 64 + n * 16 + l15;
                int g = (kk >> 1) ^ ((r >> 2) & 3);
                bf[kc][n] = *(const long long*)(
                    &bbuf[acur * 8192 + r * 64 + g * 16 + (kk & 1) * 8]);
            }
        }

        if (s + 2 < NS) STAGE(astg, s + 2);    // DMA flies under the MFMAs

        __builtin_amdgcn_s_setprio(1);
#pragma unroll
        for (int kc = 0; kc < 2; ++kc)
#pragma unroll
        for (int m = 0; m < 2; ++m)
#pragma unroll
        for (int n = 0; n < 4; ++n)
            acc[m][n] = __builtin_amdgcn_mfma_f32_16x16x32_fp8_fp8(
                af[kc][m], bf[kc][n], acc[m][n], 0, 0, 0);
        __builtin_amdgcn_s_setprio(0);

        acur = (acur == 2) ? 0 : acur + 1;
        astg = (astg == 2) ? 0 : astg + 1;
    }
#undef STAGE

    // ---- epilogue: MAX-FREE partial sum(exp(logit)) over 128 cols ----
    // |sim| <= ~1.03 -> |logit| <= 5.2 -> exp in [5e-3, 181]: no overflow.
#pragma unroll
    for (int m = 0; m < 2; ++m) {
#pragma unroll
        for (int r = 0; r < 4; ++r) {
            const int lrow = wr * 32 + m * 16 + l4 * 4 + r;   // local row 0..63
            float lg[4];
            float se = 0.f;
#pragma unroll
            for (int n = 0; n < 4; ++n) {
                lg[n] = acc[m][n][r] * 5.0f;                  // /TEMP
                se += __expf(lg[n]);
            }
            se += __shfl_xor(se, 1);
            se += __shfl_xor(se, 2);
            se += __shfl_xor(se, 4);
            se += __shfl_xor(se, 8);
            if (l15 == 0) sm_sum[lrow][wc] = se;
            const int posc = (brow + lrow) & (NB - 1);        // global row % 512
#pragma unroll
            for (int n = 0; n < 4; ++n)
                if (bcol + wc * 64 + n * 16 + l15 == posc) sm_pos[lrow] = lg[n];
        }
    }
    __syncthreads();

    if (tid < BM) {
        const int lrow = tid;
        const int grow = brow + lrow;
        psum_g[cb * NM + grow] = sm_sum[lrow][0] + sm_sum[lrow][1];
        if (((grow & (NB - 1)) >> 7) == cb) ppos_g[grow] = sm_pos[lrow];
    }
}

// ---------------------------------------------------------------------------
// Combine 4 col-block partials per row -> loss; last block writes d_out.
__global__ __launch_bounds__(256) void reduce_kernel(
        const float* __restrict__ psum_g, const float* __restrict__ ppos_g,
        float* __restrict__ acc_g, u32* __restrict__ counter,
        float* __restrict__ out) {
    const int row = blockIdx.x * 256 + threadIdx.x;   // 32 blocks x 256
    float tot = psum_g[row] + psum_g[NM + row]
              + psum_g[2 * NM + row] + psum_g[3 * NM + row];
    float term = __logf(tot) - ppos_g[row];
#pragma unroll
    for (int off = 32; off > 0; off >>= 1) term += __shfl_xor(term, off);
    __shared__ float wsum[4];
    const int lane = threadIdx.x & 63, wv = threadIdx.x >> 6;
    if (lane == 0) wsum[wv] = term;
    __syncthreads();
    if (threadIdx.x == 0) {
        atomicAdd(acc_g, wsum[0] + wsum[1] + wsum[2] + wsum[3]);
        __threadfence();
        u32 old = atomicAdd(counter, 1u);
        if (old == 31u) {                       // last block: all adds visible
            float total = atomicAdd(acc_g, 0.0f);
            out[0] = total * (1.0f / (float)NM);
        }
    }
}

extern "C" void kernel_launch(void* const* d_in, const int* in_sizes, int n_in,
                              void* d_out, int out_size, void* d_ws, size_t ws_size,
                              hipStream_t stream) {
    const float* feat = (const float*)d_in[0];

    unsigned char* an = (unsigned char*)d_ws;              // 16 MB fp8
    unsigned char* zn = an + (size_t)NM * ND;              // 1 MB fp8
    float* psum = (float*)(zn + (size_t)NB * ND);          // NCB*NM
    float* ppos = psum + NCB * NM;                         // NM
    float* accg = ppos + NM;                               // 1 float
    u32*   cntr = (u32*)(accg + 1);                        // 1 u32

    prep_kernel<<<NB, 512, 0, stream>>>(feat, an, zn, accg, cntr);
    gemm_loss_kernel<<<(NM / BM) * NCB, 256, 0, stream>>>(an, zn, psum, ppos);
    reduce_kernel<<<NM / 256, 256, 0, stream>>>(psum, ppos, accg, cntr,
                                                (float*)d_out);
}

// Round 19
// 43.021 us; speedup vs baseline: 1.8101x; 1.0347x over previous
//
#include <hip/hip_runtime.h>
#include <hip/hip_bf16.h>
#include <math.h>

#define NP 16
#define NB 512
#define ND 2048
#define NM (NP*NB)          // 8192 rows
#define BM 64
#define BN 128
#define BK 128              // 128 k-elems = 128 BYTES per row per step (fp8)
#define NS (ND/BK)          // 16 K-steps
#define NCB (NB/BN)         // 4 col-blocks

typedef __attribute__((ext_vector_type(4))) float f32x4;
typedef unsigned int u32;

__device__ inline float dot4(float4 v) {
    return v.x * v.x + v.y * v.y + v.z * v.z + v.w * v.w;
}

// ---- f32x4 -> 4 packed OCP e4m3fn bytes (HW cvt; RNE, saturating) --------
#if __has_builtin(__builtin_amdgcn_cvt_pk_fp8_f32)
__device__ inline u32 pack4_fp8(float a, float b, float c, float d) {
    int w = 0;
    w = __builtin_amdgcn_cvt_pk_fp8_f32(a, b, w, false);  // bytes 0,1
    w = __builtin_amdgcn_cvt_pk_fp8_f32(c, d, w, true);   // bytes 2,3
    return (u32)w;
}
#else
#include <hip/hip_fp8.h>
__device__ inline u32 pack4_fp8(float a, float b, float c, float d) {
    u32 w  = (u32)__hip_cvt_float_to_fp8(a, __HIP_SATFINITE, __HIP_E4M3);
    w |= (u32)__hip_cvt_float_to_fp8(b, __HIP_SATFINITE, __HIP_E4M3) << 8;
    w |= (u32)__hip_cvt_float_to_fp8(c, __HIP_SATFINITE, __HIP_E4M3) << 16;
    w |= (u32)__hip_cvt_float_to_fp8(d, __HIP_SATFINITE, __HIP_E4M3) << 24;
    return w;
}
#endif

// ---------------------------------------------------------------------------
// Prep (d-sliced, R14-verified, unchanged from R18).
__global__ __launch_bounds__(512) void prep_kernel(
        const float* __restrict__ feat,
        unsigned char* __restrict__ an,      // [NM][ND] fp8, row-normalized
        unsigned char* __restrict__ zn,      // [NB][ND] fp8, row-normalized
        float* __restrict__ accg, u32* __restrict__ cntr) {
    const int b = blockIdx.x, tid = threadIdx.x;
    const int lane = tid & 63, wv = tid >> 6;
    if (b == 0 && tid == 0) { accg[0] = 0.f; cntr[0] = 0u; }

    const int dbase = wv * 256 + lane * 4;           // float index within row
    const float4* fp4 = (const float4*)feat;

    float4 rv[16];
    float4 z = make_float4(0.f, 0.f, 0.f, 0.f);
#pragma unroll
    for (int p = 0; p < NP; ++p) {
        rv[p] = fp4[((size_t)(p * NB + b) * ND + dbase) >> 2];
        z.x += rv[p].x; z.y += rv[p].y; z.z += rv[p].z; z.w += rv[p].w;
    }

    __shared__ float sm_ssq[NP][8];
    __shared__ float sm_z[8];
    __shared__ float sm_inv[NP + 1];
#pragma unroll
    for (int p = 0; p < NP; ++p) {
        float ss = dot4(rv[p]);
#pragma unroll
        for (int off = 32; off > 0; off >>= 1) ss += __shfl_xor(ss, off);
        if (lane == 0) sm_ssq[p][wv] = ss;
    }
    {
        float zs = dot4(z);
#pragma unroll
        for (int off = 32; off > 0; off >>= 1) zs += __shfl_xor(zs, off);
        if (lane == 0) sm_z[wv] = zs;
    }
    __syncthreads();
    if (tid < NP) {
        float t = 0.f;
#pragma unroll
        for (int v = 0; v < 8; ++v) t += sm_ssq[tid][v];
        sm_inv[tid] = 1.f / fmaxf(sqrtf(t), 1e-12f);
    } else if (tid == NP) {
        float t = 0.f;
#pragma unroll
        for (int v = 0; v < 8; ++v) t += sm_z[v];
        sm_inv[NP] = 1.f / fmaxf(sqrtf(t), 1e-12f);
    }
    __syncthreads();

#pragma unroll
    for (int p = 0; p < NP; ++p) {
        const float inv = sm_inv[p];
        ((u32*)(an + (size_t)(p * NB + b) * ND))[dbase >> 2] =
            pack4_fp8(rv[p].x * inv, rv[p].y * inv, rv[p].z * inv, rv[p].w * inv);
    }
    const float iz = sm_inv[NP];
    ((u32*)(zn + (size_t)b * ND))[dbase >> 2] =
        pack4_fp8(z.x * iz, z.y * iz, z.z * iz, z.w * iz);
}

// ---------------------------------------------------------------------------
// GEMM + partial CE loss, fp8 e4m3. R18 schedule (read -> stage -> MFMA,
// runtime rotation, ONE barrier + counted vmcnt/step, XCD-affinity remap,
// max-free softmax) with BK=128: 128 B rows restore R10's measured
// conflict-free layout (row = exactly 32 banks; swizzle c ^= r&7 on 16B
// granules, same involution on stage-source and read). 16 steps, vmcnt(6).
__global__ __launch_bounds__(256, 2) void gemm_loss_kernel(
        const unsigned char* __restrict__ an, // [NM][ND] fp8
        const unsigned char* __restrict__ zn, // [NB][ND] fp8
        float* __restrict__ psum_g,           // [NCB][NM]
        float* __restrict__ ppos_g) {         // [NM]
    __shared__ __align__(16) unsigned char abuf[3 * BM * BK];  // 3 x 8 KB
    __shared__ __align__(16) unsigned char bbuf[3 * BN * BK];  // 3 x 16 KB
    __shared__ float sm_sum[BM][2];
    __shared__ float sm_pos[BM];

    const int tid  = threadIdx.x;
    const int lane = tid & 63;
    const int w    = tid >> 6;       // 0..3
    const int wr   = w >> 1;         // row strip 0..1 (32 rows each)
    const int wc   = w & 1;          // col strip 0..1 (64 cols each)
    const int l15  = lane & 15;
    const int l4   = lane >> 4;      // 0..3
    // XCD-affinity remap (R18-verified): all 4 cb's of a row-panel share XCD.
    const int xcd    = blockIdx.x & 7;
    const int slot   = blockIdx.x >> 3;          // 0..63
    const int cb     = slot & 3;
    const int rowblk = xcd + 8 * (slot >> 2);    // 0..127, bijective
    const int brow = rowblk * BM;
    const int bcol = cb * BN;

    f32x4 acc[2][4] = {};

    // Staging: 16B granules, row r = chunk>>3, granule c = chunk&7,
    // swizzled cs = c ^ (r&7). Thread tid covers A chunks {tid, 256+tid}
    // (rows +0,+32) and B chunks {i*256+tid} (rows +32i) — r&7 identical for
    // all (row offsets are multiples of 32), so ONE swizzle constant.
    const int sr  = tid >> 3;                        // base row 0..31
    const int scs = (tid & 7) ^ (sr & 7);            // swizzled granule
    const unsigned char* asrc = an + (size_t)(brow + sr) * ND + scs * 16;
    const unsigned char* bsrc = zn + (size_t)(bcol + sr) * ND + scs * 16;

#define STAGE(BI, S) do {                                                     \
        const int koB_ = (S) * BK;                                            \
        __builtin_amdgcn_global_load_lds((const u32*)(asrc + koB_),           \
            (u32*)(&abuf[(BI) * 8192 + tid * 16]), 16, 0, 0);                 \
        __builtin_amdgcn_global_load_lds((const u32*)(asrc + 32 * ND + koB_), \
            (u32*)(&abuf[(BI) * 8192 + 4096 + tid * 16]), 16, 0, 0);          \
        _Pragma("unroll")                                                     \
        for (int i = 0; i < 4; ++i) {                                         \
            __builtin_amdgcn_global_load_lds(                                 \
                (const u32*)(bsrc + (size_t)(32 * i) * ND + koB_),            \
                (u32*)(&bbuf[(BI) * 16384 + i * 4096 + tid * 16]), 16, 0, 0); \
        }                                                                     \
    } while (0)

    STAGE(0, 0);
    STAGE(1, 1);

    int acur = 0, astg = 2;
    for (int s = 0; s < NS; ++s) {
        if (s + 1 < NS) asm volatile("s_waitcnt vmcnt(6)" ::: "memory");
        else            asm volatile("s_waitcnt vmcnt(0)" ::: "memory");
        __builtin_amdgcn_sched_barrier(0);
        __builtin_amdgcn_s_barrier();          // buf staged by ALL waves;
        __builtin_amdgcn_sched_barrier(0);     // prev-step reads all retired

        // frag reads: 8B chunk kk = kc*4+l4 (kc 0..3) of a 128B row;
        // 16B granule g = (kk>>1) ^ (r&7), low half (kk&1)=(l4&1).
        long long af[4][2], bf[4][4];
#pragma unroll
        for (int kc = 0; kc < 4; ++kc) {
            const int g16 = kc * 2 + (l4 >> 1);
            const int lo8 = (l4 & 1) * 8;
#pragma unroll
            for (int m = 0; m < 2; ++m) {
                int r = wr * 32 + m * 16 + l15;
                int g = g16 ^ (r & 7);
                af[kc][m] = *(const long long*)(
                    &abuf[acur * 8192 + r * BK + g * 16 + lo8]);
            }
#pragma unroll
            for (int n = 0; n < 4; ++n) {
                int r = wc * 64 + n * 16 + l15;
                int g = g16 ^ (r & 7);
                bf[kc][n] = *(const long long*)(
                    &bbuf[acur * 16384 + r * BK + g * 16 + lo8]);
            }
        }

        if (s + 2 < NS) STAGE(astg, s + 2);    // DMA flies under the MFMAs

        __builtin_amdgcn_s_setprio(1);
#pragma unroll
        for (int kc = 0; kc < 4; ++kc)
#pragma unroll
        for (int m = 0; m < 2; ++m)
#pragma unroll
        for (int n = 0; n < 4; ++n)
            acc[m][n] = __builtin_amdgcn_mfma_f32_16x16x32_fp8_fp8(
                af[kc][m], bf[kc][n], acc[m][n], 0, 0, 0);
        __builtin_amdgcn_s_setprio(0);

        acur = (acur == 2) ? 0 : acur + 1;
        astg = (astg == 2) ? 0 : astg + 1;
    }
#undef STAGE

    // ---- epilogue: MAX-FREE partial sum(exp(logit)) over 128 cols ----
    // |sim| <= ~1.03 -> |logit| <= 5.2 -> exp in [5e-3, 181]: no overflow.
#pragma unroll
    for (int m = 0; m < 2; ++m) {
#pragma unroll
        for (int r = 0; r < 4; ++r) {
            const int lrow = wr * 32 + m * 16 + l4 * 4 + r;   // local row 0..63
            float lg[4];
            float se = 0.f;
#pragma unroll
            for (int n = 0; n < 4; ++n) {
                lg[n] = acc[m][n][r] * 5.0f;                  // /TEMP
                se += __expf(lg[n]);
            }
            se += __shfl_xor(se, 1);
            se += __shfl_xor(se, 2);
            se += __shfl_xor(se, 4);
            se += __shfl_xor(se, 8);
            if (l15 == 0) sm_sum[lrow][wc] = se;
            const int posc = (brow + lrow) & (NB - 1);        // global row % 512
#pragma unroll
            for (int n = 0; n < 4; ++n)
                if (bcol + wc * 64 + n * 16 + l15 == posc) sm_pos[lrow] = lg[n];
        }
    }
    __syncthreads();

    if (tid < BM) {
        const int lrow = tid;
        const int grow = brow + lrow;
        psum_g[cb * NM + grow] = sm_sum[lrow][0] + sm_sum[lrow][1];
        if (((grow & (NB - 1)) >> 7) == cb) ppos_g[grow] = sm_pos[lrow];
    }
}

// ---------------------------------------------------------------------------
// Combine 4 col-block partials per row -> loss; last block writes d_out.
__global__ __launch_bounds__(256) void reduce_kernel(
        const float* __restrict__ psum_g, const float* __restrict__ ppos_g,
        float* __restrict__ acc_g, u32* __restrict__ counter,
        float* __restrict__ out) {
    const int row = blockIdx.x * 256 + threadIdx.x;   // 32 blocks x 256
    float tot = psum_g[row] + psum_g[NM + row]
              + psum_g[2 * NM + row] + psum_g[3 * NM + row];
    float term = __logf(tot) - ppos_g[row];
#pragma unroll
    for (int off = 32; off > 0; off >>= 1) term += __shfl_xor(term, off);
    __shared__ float wsum[4];
    const int lane = threadIdx.x & 63, wv = threadIdx.x >> 6;
    if (lane == 0) wsum[wv] = term;
    __syncthreads();
    if (threadIdx.x == 0) {
        atomicAdd(acc_g, wsum[0] + wsum[1] + wsum[2] + wsum[3]);
        __threadfence();
        u32 old = atomicAdd(counter, 1u);
        if (old == 31u) {                       // last block: all adds visible
            float total = atomicAdd(acc_g, 0.0f);
            out[0] = total * (1.0f / (float)NM);
        }
    }
}

extern "C" void kernel_launch(void* const* d_in, const int* in_sizes, int n_in,
                              void* d_out, int out_size, void* d_ws, size_t ws_size,
                              hipStream_t stream) {
    const float* feat = (const float*)d_in[0];

    unsigned char* an = (unsigned char*)d_ws;              // 16 MB fp8
    unsigned char* zn = an + (size_t)NM * ND;              // 1 MB fp8
    float* psum = (float*)(zn + (size_t)NB * ND);          // NCB*NM
    float* ppos = psum + NCB * NM;                         // NM
    float* accg = ppos + NM;                               // 1 float
    u32*   cntr = (u32*)(accg + 1);                        // 1 u32

    prep_kernel<<<NB, 512, 0, stream>>>(feat, an, zn, accg, cntr);
    gemm_loss_kernel<<<(NM / BM) * NCB, 256, 0, stream>>>(an, zn, psum, ppos);
    reduce_kernel<<<NM / 256, 256, 0, stream>>>(psum, ppos, accg, cntr,
                                                (float*)d_out);
}